// Round 2
// baseline (351.417 us; speedup 1.0000x reference)
//
#include <hip/hip_runtime.h>

// GAE scan: T=2048, N=4096, fp32. FUSED single-pass kernel with a MANUAL
// software grid barrier (hipLaunchCooperativeKernel failed on this harness —
// round-1 output was all zeros => launch never ran).
//
// Phase 1: per-(chunk, env4) compose affine (A, P), stashing delta/cc/v for
//   all CHUNK_L steps in registers (48 float4 = 192 VGPRs).
// Barrier: release fence -> syncthreads -> tid0 atomicAdd+spin -> syncthreads
//   -> acquire fence. Safe: __launch_bounds__(256,2) caps VGPR at 256 =>
//   2 blocks/CU guaranteed; grid = 512 = 2*256 CUs => ALL blocks co-resident,
//   so the barrier cannot deadlock regardless of dispatch order. Spin is
//   bounded so a protocol bug fails visibly instead of hanging.
// Phase 2: coalesced L2-hot look-back over chunk summaries above (b = A*b+P).
// Phase 3: replay the chunk FROM REGISTERS (no input re-read), write adv+ret.
//
// Traffic: ~100 MB read + ~71 MB write vs ~272 MB for the 2-kernel version.
// Counter lives at ws+4MiB, memset to 0 on the stream each launch (graph-
// replay and workspace-poison safe). ws_size guard falls back to the proven
// 2-kernel path.

#define T_LEN    2048
#define N_ENV    4096
#define NV4      (N_ENV / 4)          // 1024 float4 columns
#define N_CHUNKS 128
#define CHUNK_L  (T_LEN / N_CHUNKS)   // 16
#define NBLK     ((N_CHUNKS * NV4) / 256)   // 512 blocks

static constexpr float GAMMA = 0.99f;
static constexpr float GL    = 0.99f * 0.95f;   // gamma * gae_lambda

__global__ __launch_bounds__(256, 2) void gae_fused(
    const float4* __restrict__ rewards,   // [T_LEN][NV4]
    const float4* __restrict__ values,
    const float4* __restrict__ dones,
    float4* __restrict__ Abuf,            // [N_CHUNKS][NV4] workspace
    float4* __restrict__ Pbuf,
    int*    __restrict__ counter,         // memset to 0 before launch
    float4* __restrict__ out)             // [2*T_LEN][NV4]: advantages, returns
{
    const int idx = blockIdx.x * blockDim.x + threadIdx.x;   // c*NV4 + n4
    const int n4 = idx & (NV4 - 1);
    const int c  = idx >> 10;
    const int t_hi = c * CHUNK_L + (CHUNK_L - 1);

    float4 v_next, d_next;
    if (c == N_CHUNKS - 1) {
        v_next = make_float4(0.f, 0.f, 0.f, 0.f);
        d_next = make_float4(1.f, 1.f, 1.f, 1.f);
    } else {
        v_next = values[(t_hi + 1) * NV4 + n4];
        d_next = dones [(t_hi + 1) * NV4 + n4];
    }

    // Register stash for the replay phase: delta, cc = GL*nt, v.
    // Fully-unrolled loops => static indices => stays in VGPRs (no scratch).
    float4 dl[CHUNK_L], cc[CHUNK_L], vv[CHUNK_L];

    float4 A = make_float4(1.f, 1.f, 1.f, 1.f);
    float4 P = make_float4(0.f, 0.f, 0.f, 0.f);

    #pragma unroll
    for (int i = 0; i < CHUNK_L; ++i) {
        const int t = t_hi - i;
        const float4 r = rewards[t * NV4 + n4];
        const float4 v = values [t * NV4 + n4];
        const float4 d = dones  [t * NV4 + n4];
        float4 dli, cci;
        #define STEP(X) { \
            const float nt    = 1.0f - d_next.X; \
            const float delta = fmaf(GAMMA * v_next.X, nt, r.X) - v.X; \
            const float co    = GL * nt; \
            dli.X = delta; cci.X = co; \
            P.X = fmaf(co, P.X, delta); \
            A.X = co * A.X; \
            v_next.X = v.X; d_next.X = d.X; }
        STEP(x) STEP(y) STEP(z) STEP(w)
        #undef STEP
        dl[i] = dli; cc[i] = cci; vv[i] = v;
    }
    Abuf[idx] = A;
    Pbuf[idx] = P;

    // ---- software grid barrier (all NBLK blocks co-resident) ----
    __threadfence();       // release: write back A/P past per-XCD L2
    __syncthreads();       // all threads in block have fenced their stores
    if (threadIdx.x == 0) {
        __hip_atomic_fetch_add(counter, 1, __ATOMIC_ACQ_REL,
                               __HIP_MEMORY_SCOPE_AGENT);
        int spins = 0;
        while (__hip_atomic_load(counter, __ATOMIC_RELAXED,
                                 __HIP_MEMORY_SCOPE_AGENT) < NBLK &&
               spins < (1 << 26)) {        // bounded: fail visibly, never hang
            __builtin_amdgcn_s_sleep(2);
            ++spins;
        }
    }
    __syncthreads();
    __threadfence();       // acquire: invalidate stale L1/L2 before reading A/P

    // Look-back: incoming adv = suffix composition of chunk affines above,
    // applied to 0. A/P are 2 MB each -> L2/LLC-resident, coalesced reads.
    float4 adv = make_float4(0.f, 0.f, 0.f, 0.f);
    #pragma unroll 4
    for (int c2 = N_CHUNKS - 1; c2 > c; --c2) {
        const float4 a = Abuf[c2 * NV4 + n4];
        const float4 p = Pbuf[c2 * NV4 + n4];
        adv.x = fmaf(a.x, adv.x, p.x);
        adv.y = fmaf(a.y, adv.y, p.y);
        adv.z = fmaf(a.z, adv.z, p.z);
        adv.w = fmaf(a.w, adv.w, p.w);
    }

    // Replay from the register stash; no global re-read of inputs.
    #pragma unroll
    for (int i = 0; i < CHUNK_L; ++i) {
        const int t = t_hi - i;
        float4 ret;
        adv.x = fmaf(cc[i].x, adv.x, dl[i].x);  ret.x = adv.x + vv[i].x;
        adv.y = fmaf(cc[i].y, adv.y, dl[i].y);  ret.y = adv.y + vv[i].y;
        adv.z = fmaf(cc[i].z, adv.z, dl[i].z);  ret.z = adv.z + vv[i].z;
        adv.w = fmaf(cc[i].w, adv.w, dl[i].w);  ret.w = adv.w + vv[i].w;
        out[t * NV4 + n4]           = adv;   // advantages
        out[(T_LEN + t) * NV4 + n4] = ret;   // returns
    }
}

// ---- fallback: proven 2-kernel path (used only if ws_size is too small) ----

__global__ __launch_bounds__(256) void gae_phase1(
    const float4* __restrict__ rewards,
    const float4* __restrict__ values,
    const float4* __restrict__ dones,
    float4* __restrict__ Aout,
    float4* __restrict__ Pout)
{
    const int idx = blockIdx.x * blockDim.x + threadIdx.x;
    const int n4 = idx & (NV4 - 1);
    const int c  = idx >> 10;
    const int t_hi = c * CHUNK_L + (CHUNK_L - 1);

    float4 v_next, d_next;
    if (c == N_CHUNKS - 1) {
        v_next = make_float4(0.f, 0.f, 0.f, 0.f);
        d_next = make_float4(1.f, 1.f, 1.f, 1.f);
    } else {
        v_next = values[(t_hi + 1) * NV4 + n4];
        d_next = dones [(t_hi + 1) * NV4 + n4];
    }

    float4 A = make_float4(1.f, 1.f, 1.f, 1.f);
    float4 P = make_float4(0.f, 0.f, 0.f, 0.f);

    #pragma unroll
    for (int i = 0; i < CHUNK_L; ++i) {
        const int t = t_hi - i;
        const float4 r = rewards[t * NV4 + n4];
        const float4 v = values [t * NV4 + n4];
        const float4 d = dones  [t * NV4 + n4];
        #define STEP(X) { \
            const float nt    = 1.0f - d_next.X; \
            const float delta = fmaf(GAMMA * v_next.X, nt, r.X) - v.X; \
            const float co    = GL * nt; \
            P.X = fmaf(co, P.X, delta); \
            A.X = co * A.X; \
            v_next.X = v.X; d_next.X = d.X; }
        STEP(x) STEP(y) STEP(z) STEP(w)
        #undef STEP
    }
    Aout[idx] = A;
    Pout[idx] = P;
}

__global__ __launch_bounds__(256) void gae_phase23(
    const float4* __restrict__ rewards,
    const float4* __restrict__ values,
    const float4* __restrict__ dones,
    const float4* __restrict__ Ain,
    const float4* __restrict__ Pin,
    float4* __restrict__ out)
{
    const int idx = blockIdx.x * blockDim.x + threadIdx.x;
    const int n4 = idx & (NV4 - 1);
    const int c  = idx >> 10;
    const int t_hi = c * CHUNK_L + (CHUNK_L - 1);

    float4 adv = make_float4(0.f, 0.f, 0.f, 0.f);
    #pragma unroll 4
    for (int c2 = N_CHUNKS - 1; c2 > c; --c2) {
        const float4 a = Ain[c2 * NV4 + n4];
        const float4 p = Pin[c2 * NV4 + n4];
        adv.x = fmaf(a.x, adv.x, p.x);
        adv.y = fmaf(a.y, adv.y, p.y);
        adv.z = fmaf(a.z, adv.z, p.z);
        adv.w = fmaf(a.w, adv.w, p.w);
    }

    float4 v_next, d_next;
    if (c == N_CHUNKS - 1) {
        v_next = make_float4(0.f, 0.f, 0.f, 0.f);
        d_next = make_float4(1.f, 1.f, 1.f, 1.f);
    } else {
        v_next = values[(t_hi + 1) * NV4 + n4];
        d_next = dones [(t_hi + 1) * NV4 + n4];
    }

    #pragma unroll
    for (int i = 0; i < CHUNK_L; ++i) {
        const int t = t_hi - i;
        const float4 r = rewards[t * NV4 + n4];
        const float4 v = values [t * NV4 + n4];
        const float4 d = dones  [t * NV4 + n4];
        float4 ret;
        #define STEP(X) { \
            const float nt    = 1.0f - d_next.X; \
            const float delta = fmaf(GAMMA * v_next.X, nt, r.X) - v.X; \
            const float co    = GL * nt; \
            adv.X = fmaf(co, adv.X, delta); \
            ret.X = adv.X + v.X; \
            v_next.X = v.X; d_next.X = d.X; }
        STEP(x) STEP(y) STEP(z) STEP(w)
        #undef STEP
        out[t * NV4 + n4]           = adv;
        out[(T_LEN + t) * NV4 + n4] = ret;
    }
}

extern "C" void kernel_launch(void* const* d_in, const int* in_sizes, int n_in,
                              void* d_out, int out_size, void* d_ws, size_t ws_size,
                              hipStream_t stream) {
    const float4* rewards = (const float4*)d_in[0];
    const float4* values  = (const float4*)d_in[1];
    const float4* dones   = (const float4*)d_in[2];
    float4* out = (float4*)d_out;

    // Workspace: A | P (2 MiB each) | barrier counter.
    float4* A = (float4*)d_ws;
    float4* P = A + (size_t)N_CHUNKS * NV4;
    const size_t apBytes = (size_t)2 * N_CHUNKS * NV4 * sizeof(float4); // 4 MiB

    if (ws_size >= apBytes + sizeof(int)) {
        int* counter = (int*)((char*)d_ws + apBytes);
        hipMemsetAsync(counter, 0, sizeof(int), stream);   // graph-capturable
        gae_fused<<<NBLK, 256, 0, stream>>>(
            rewards, values, dones, A, P, counter, out);
    } else {
        gae_phase1<<<NBLK, 256, 0, stream>>>(rewards, values, dones, A, P);
        gae_phase23<<<NBLK, 256, 0, stream>>>(rewards, values, dones, A, P, out);
    }
}

// Round 3
// 325.979 us; speedup vs baseline: 1.0780x; 1.0780x over previous
//
#include <hip/hip_runtime.h>

// GAE scan: T=2048, N=4096, fp32. FUSED single-pass kernel, manual grid barrier.
//
// Round-2 post-mortem: compiler targeted 4 waves/EU (VGPR_Count=128) and
// SPILLED the 192-reg stash to scratch (WRITE_SIZE 105.5 MB vs 71 expected,
// ~64 fp32/thread spilled) -> 250 us scratch-latency-bound. Fix:
//   (a) amdgpu_waves_per_eu(2,2) pins exactly 2 waves/EU (VGPR cap 256,
//       allocator stops spilling to chase occupancy);
//   (b) stash shrunk to dl/cc only (128 VGPRs); phase 3 re-reads `values`
//       (32 MB, L3-resident — FETCH=71.5MB in round 2 proves inputs L3-fit).
//
// Phase 1: per-(chunk, env4) compose affine (A, P), stash delta/cc in regs.
// Barrier: release fence -> syncthreads -> tid0 atomicAdd+bounded-spin ->
//   syncthreads -> acquire fence. Safe: VGPR<=256 => 2 blocks/CU => all 512
//   blocks co-resident on 256 CUs regardless of dispatch order.
// Phase 2: coalesced L2-hot look-back over chunk affines above (b = A*b+P).
// Phase 3: replay from regs (+ L3-hot values re-read), write adv + ret.

#define T_LEN    2048
#define N_ENV    4096
#define NV4      (N_ENV / 4)          // 1024 float4 columns
#define N_CHUNKS 128
#define CHUNK_L  (T_LEN / N_CHUNKS)   // 16
#define NBLK     ((N_CHUNKS * NV4) / 256)   // 512 blocks

static constexpr float GAMMA = 0.99f;
static constexpr float GL    = 0.99f * 0.95f;   // gamma * gae_lambda

__global__ void
__launch_bounds__(256)
__attribute__((amdgpu_waves_per_eu(2, 2)))
gae_fused(
    const float4* __restrict__ rewards,   // [T_LEN][NV4]
    const float4* __restrict__ values,
    const float4* __restrict__ dones,
    float4* __restrict__ Abuf,            // [N_CHUNKS][NV4] workspace
    float4* __restrict__ Pbuf,
    int*    __restrict__ counter,         // memset to 0 before launch
    float4* __restrict__ out)             // [2*T_LEN][NV4]: advantages, returns
{
    const int idx = blockIdx.x * blockDim.x + threadIdx.x;   // c*NV4 + n4
    const int n4 = idx & (NV4 - 1);
    const int c  = idx >> 10;
    const int t_hi = c * CHUNK_L + (CHUNK_L - 1);

    float4 v_next, d_next;
    if (c == N_CHUNKS - 1) {
        v_next = make_float4(0.f, 0.f, 0.f, 0.f);
        d_next = make_float4(1.f, 1.f, 1.f, 1.f);
    } else {
        v_next = values[(t_hi + 1) * NV4 + n4];
        d_next = dones [(t_hi + 1) * NV4 + n4];
    }

    // Register stash for the replay phase: delta and cc = GL*nt only
    // (128 VGPRs). Fully-unrolled => static indices => no scratch.
    float4 dl[CHUNK_L], cc[CHUNK_L];

    float4 A = make_float4(1.f, 1.f, 1.f, 1.f);
    float4 P = make_float4(0.f, 0.f, 0.f, 0.f);

    #pragma unroll
    for (int i = 0; i < CHUNK_L; ++i) {
        const int t = t_hi - i;
        const float4 r = rewards[t * NV4 + n4];
        const float4 v = values [t * NV4 + n4];
        const float4 d = dones  [t * NV4 + n4];
        float4 dli, cci;
        #define STEP(X) { \
            const float nt    = 1.0f - d_next.X; \
            const float delta = fmaf(GAMMA * v_next.X, nt, r.X) - v.X; \
            const float co    = GL * nt; \
            dli.X = delta; cci.X = co; \
            P.X = fmaf(co, P.X, delta); \
            A.X = co * A.X; \
            v_next.X = v.X; d_next.X = d.X; }
        STEP(x) STEP(y) STEP(z) STEP(w)
        #undef STEP
        dl[i] = dli; cc[i] = cci;
    }
    Abuf[idx] = A;
    Pbuf[idx] = P;

    // ---- software grid barrier (all NBLK blocks co-resident) ----
    __threadfence();       // release: write A/P back past per-XCD L2
    __syncthreads();
    if (threadIdx.x == 0) {
        __hip_atomic_fetch_add(counter, 1, __ATOMIC_ACQ_REL,
                               __HIP_MEMORY_SCOPE_AGENT);
        int spins = 0;
        while (__hip_atomic_load(counter, __ATOMIC_RELAXED,
                                 __HIP_MEMORY_SCOPE_AGENT) < NBLK &&
               spins < (1 << 26)) {        // bounded: fail visibly, never hang
            __builtin_amdgcn_s_sleep(2);
            ++spins;
        }
    }
    __syncthreads();
    __threadfence();       // acquire: no stale L1/L2 lines for A/P reads

    // Look-back: incoming adv = suffix composition of chunk affines above,
    // applied to 0. A/P are 2 MB each -> L2/LLC-resident, coalesced reads.
    float4 adv = make_float4(0.f, 0.f, 0.f, 0.f);
    #pragma unroll 4
    for (int c2 = N_CHUNKS - 1; c2 > c; --c2) {
        const float4 a = Abuf[c2 * NV4 + n4];
        const float4 p = Pbuf[c2 * NV4 + n4];
        adv.x = fmaf(a.x, adv.x, p.x);
        adv.y = fmaf(a.y, adv.y, p.y);
        adv.z = fmaf(a.z, adv.z, p.z);
        adv.w = fmaf(a.w, adv.w, p.w);
    }

    // Replay from the register stash; re-read only `values` (L3-hot).
    #pragma unroll
    for (int i = 0; i < CHUNK_L; ++i) {
        const int t = t_hi - i;
        const float4 v = values[t * NV4 + n4];
        float4 ret;
        adv.x = fmaf(cc[i].x, adv.x, dl[i].x);  ret.x = adv.x + v.x;
        adv.y = fmaf(cc[i].y, adv.y, dl[i].y);  ret.y = adv.y + v.y;
        adv.z = fmaf(cc[i].z, adv.z, dl[i].z);  ret.z = adv.z + v.z;
        adv.w = fmaf(cc[i].w, adv.w, dl[i].w);  ret.w = adv.w + v.w;
        out[t * NV4 + n4]           = adv;   // advantages
        out[(T_LEN + t) * NV4 + n4] = ret;   // returns
    }
}

// ---- fallback: proven 2-kernel path (used only if ws_size is too small) ----

__global__ __launch_bounds__(256) void gae_phase1(
    const float4* __restrict__ rewards,
    const float4* __restrict__ values,
    const float4* __restrict__ dones,
    float4* __restrict__ Aout,
    float4* __restrict__ Pout)
{
    const int idx = blockIdx.x * blockDim.x + threadIdx.x;
    const int n4 = idx & (NV4 - 1);
    const int c  = idx >> 10;
    const int t_hi = c * CHUNK_L + (CHUNK_L - 1);

    float4 v_next, d_next;
    if (c == N_CHUNKS - 1) {
        v_next = make_float4(0.f, 0.f, 0.f, 0.f);
        d_next = make_float4(1.f, 1.f, 1.f, 1.f);
    } else {
        v_next = values[(t_hi + 1) * NV4 + n4];
        d_next = dones [(t_hi + 1) * NV4 + n4];
    }

    float4 A = make_float4(1.f, 1.f, 1.f, 1.f);
    float4 P = make_float4(0.f, 0.f, 0.f, 0.f);

    #pragma unroll
    for (int i = 0; i < CHUNK_L; ++i) {
        const int t = t_hi - i;
        const float4 r = rewards[t * NV4 + n4];
        const float4 v = values [t * NV4 + n4];
        const float4 d = dones  [t * NV4 + n4];
        #define STEP(X) { \
            const float nt    = 1.0f - d_next.X; \
            const float delta = fmaf(GAMMA * v_next.X, nt, r.X) - v.X; \
            const float co    = GL * nt; \
            P.X = fmaf(co, P.X, delta); \
            A.X = co * A.X; \
            v_next.X = v.X; d_next.X = d.X; }
        STEP(x) STEP(y) STEP(z) STEP(w)
        #undef STEP
    }
    Aout[idx] = A;
    Pout[idx] = P;
}

__global__ __launch_bounds__(256) void gae_phase23(
    const float4* __restrict__ rewards,
    const float4* __restrict__ values,
    const float4* __restrict__ dones,
    const float4* __restrict__ Ain,
    const float4* __restrict__ Pin,
    float4* __restrict__ out)
{
    const int idx = blockIdx.x * blockDim.x + threadIdx.x;
    const int n4 = idx & (NV4 - 1);
    const int c  = idx >> 10;
    const int t_hi = c * CHUNK_L + (CHUNK_L - 1);

    float4 adv = make_float4(0.f, 0.f, 0.f, 0.f);
    #pragma unroll 4
    for (int c2 = N_CHUNKS - 1; c2 > c; --c2) {
        const float4 a = Ain[c2 * NV4 + n4];
        const float4 p = Pin[c2 * NV4 + n4];
        adv.x = fmaf(a.x, adv.x, p.x);
        adv.y = fmaf(a.y, adv.y, p.y);
        adv.z = fmaf(a.z, adv.z, p.z);
        adv.w = fmaf(a.w, adv.w, p.w);
    }

    float4 v_next, d_next;
    if (c == N_CHUNKS - 1) {
        v_next = make_float4(0.f, 0.f, 0.f, 0.f);
        d_next = make_float4(1.f, 1.f, 1.f, 1.f);
    } else {
        v_next = values[(t_hi + 1) * NV4 + n4];
        d_next = dones [(t_hi + 1) * NV4 + n4];
    }

    #pragma unroll
    for (int i = 0; i < CHUNK_L; ++i) {
        const int t = t_hi - i;
        const float4 r = rewards[t * NV4 + n4];
        const float4 v = values [t * NV4 + n4];
        const float4 d = dones  [t * NV4 + n4];
        float4 ret;
        #define STEP(X) { \
            const float nt    = 1.0f - d_next.X; \
            const float delta = fmaf(GAMMA * v_next.X, nt, r.X) - v.X; \
            const float co    = GL * nt; \
            adv.X = fmaf(co, adv.X, delta); \
            ret.X = adv.X + v.X; \
            v_next.X = v.X; d_next.X = d.X; }
        STEP(x) STEP(y) STEP(z) STEP(w)
        #undef STEP
        out[t * NV4 + n4]           = adv;
        out[(T_LEN + t) * NV4 + n4] = ret;
    }
}

extern "C" void kernel_launch(void* const* d_in, const int* in_sizes, int n_in,
                              void* d_out, int out_size, void* d_ws, size_t ws_size,
                              hipStream_t stream) {
    const float4* rewards = (const float4*)d_in[0];
    const float4* values  = (const float4*)d_in[1];
    const float4* dones   = (const float4*)d_in[2];
    float4* out = (float4*)d_out;

    // Workspace: A | P (2 MiB each) | barrier counter.
    float4* A = (float4*)d_ws;
    float4* P = A + (size_t)N_CHUNKS * NV4;
    const size_t apBytes = (size_t)2 * N_CHUNKS * NV4 * sizeof(float4); // 4 MiB

    if (ws_size >= apBytes + sizeof(int)) {
        int* counter = (int*)((char*)d_ws + apBytes);
        hipMemsetAsync(counter, 0, sizeof(int), stream);   // graph-capturable
        gae_fused<<<NBLK, 256, 0, stream>>>(
            rewards, values, dones, A, P, counter, out);
    } else {
        gae_phase1<<<NBLK, 256, 0, stream>>>(rewards, values, dones, A, P);
        gae_phase23<<<NBLK, 256, 0, stream>>>(rewards, values, dones, A, P, out);
    }
}

// Round 4
// 186.419 us; speedup vs baseline: 1.8851x; 1.7486x over previous
//
#include <hip/hip_runtime.h>

// GAE scan: T=2048, N=4096, fp32. 3-kernel chunked linear-recurrence scan.
//
// Round-3 post-mortem: fused grid-barrier kernel was LATENCY-bound (690 GB/s,
// VALUBusy 1.5%): the 512-block co-residency cap (8 waves/CU) x the 128-VGPR
// register stash strangled memory-level parallelism (~8 outstanding loads/wave
// -> 0.7 TB/s, exactly as measured). Fusion saved ~100 MB but cost 4x BW.
//
// This version abandons the barrier and attacks occupancy instead:
//   K1 gae_sum : per-(chunk, env4) affine (A,P).  C=512 chunks (CHUNK_L=4)
//                -> 2048 blocks = 32 waves/CU (baseline C=128 had only 8).
//   K2 gae_scan: per env-column parallel SUFFIX SCAN of the 512 chunk affines
//                (Hillis-Steele in LDS). Replaces the O(C^2) look-back that
//                previously made C>128 uneconomical (~1 GB L2 at C=256).
//                Writes Inc[c][n4] = advantage entering chunk c from above.
//   K3 gae_out : read Inc, replay 4 steps (inputs L3-hot from K1),
//                write advantages + returns.
// No co-residency assumptions anywhere; blocks may run in any order/batches.

#define T_LEN    2048
#define N_ENV    4096
#define NV4      (N_ENV / 4)          // 1024 float4 columns
#define N_CHUNKS 512
#define CHUNK_L  (T_LEN / N_CHUNKS)   // 4
#define NBLK1    ((N_CHUNKS * NV4) / 256)   // 2048 blocks

static constexpr float GAMMA = 0.99f;
static constexpr float GL    = 0.99f * 0.95f;   // gamma * gae_lambda

// ---- K1: per-chunk affine composition -------------------------------------
__global__ __launch_bounds__(256) void gae_sum(
    const float4* __restrict__ rewards,   // [T_LEN][NV4]
    const float4* __restrict__ values,
    const float4* __restrict__ dones,
    float4* __restrict__ Aout,            // [N_CHUNKS][NV4]
    float4* __restrict__ Pout)
{
    const int idx = blockIdx.x * blockDim.x + threadIdx.x;   // c*NV4 + n4
    const int n4 = idx & (NV4 - 1);
    const int c  = idx >> 10;
    const int t_hi = c * CHUNK_L + (CHUNK_L - 1);

    float4 v_next, d_next;
    if (c == N_CHUNKS - 1) {
        v_next = make_float4(0.f, 0.f, 0.f, 0.f);
        d_next = make_float4(1.f, 1.f, 1.f, 1.f);
    } else {
        v_next = values[(t_hi + 1) * NV4 + n4];
        d_next = dones [(t_hi + 1) * NV4 + n4];
    }

    float4 A = make_float4(1.f, 1.f, 1.f, 1.f);
    float4 P = make_float4(0.f, 0.f, 0.f, 0.f);

    #pragma unroll
    for (int i = 0; i < CHUNK_L; ++i) {
        const int t = t_hi - i;
        const float4 r = rewards[t * NV4 + n4];
        const float4 v = values [t * NV4 + n4];
        const float4 d = dones  [t * NV4 + n4];
        #define STEP(X) { \
            const float nt    = 1.0f - d_next.X; \
            const float delta = fmaf(GAMMA * v_next.X, nt, r.X) - v.X; \
            const float co    = GL * nt; \
            P.X = fmaf(co, P.X, delta); \
            A.X = co * A.X; \
            v_next.X = v.X; d_next.X = d.X; }
        STEP(x) STEP(y) STEP(z) STEP(w)
        #undef STEP
    }
    Aout[idx] = A;
    Pout[idx] = P;
}

// ---- K2: per-column suffix scan of chunk affines --------------------------
// Thread c of block n4 holds f_c = (A,P); scan composes S_c = f_c o f_{c+1}
// o ... o f_{C-1}; the advantage entering chunk c is Inc[c] = S_{c+1}.P.
// Combine rule (outer o inner): (a1,p1) o (a2,p2) = (a1*a2, a1*p2 + p1).
__global__ __launch_bounds__(512) void gae_scan(
    const float4* __restrict__ Ain,    // [N_CHUNKS][NV4]
    const float4* __restrict__ Pin,
    float4* __restrict__ Inc)          // [N_CHUNKS][NV4]
{
    __shared__ float4 sA[2][N_CHUNKS];   // 16 KB
    __shared__ float4 sP[2][N_CHUNKS];   // 16 KB
    const int n4 = blockIdx.x;
    const int c  = threadIdx.x;

    float4 a = Ain[c * NV4 + n4];
    float4 p = Pin[c * NV4 + n4];
    int cur = 0;
    sA[0][c] = a; sP[0][c] = p;
    __syncthreads();

    #pragma unroll
    for (int d = 1; d < N_CHUNKS; d <<= 1) {
        float4 na = a, np = p;
        if (c + d < N_CHUNKS) {
            const float4 a2 = sA[cur][c + d];
            const float4 p2 = sP[cur][c + d];
            na.x = a.x * a2.x;  np.x = fmaf(a.x, p2.x, p.x);
            na.y = a.y * a2.y;  np.y = fmaf(a.y, p2.y, p.y);
            na.z = a.z * a2.z;  np.z = fmaf(a.z, p2.z, p.z);
            na.w = a.w * a2.w;  np.w = fmaf(a.w, p2.w, p.w);
        }
        sA[cur ^ 1][c] = na; sP[cur ^ 1][c] = np;
        __syncthreads();
        a = na; p = np; cur ^= 1;
    }

    // Inc[c] = P-component of S_{c+1}; chunk C-1 gets the zero bootstrap.
    float4 inc = (c == N_CHUNKS - 1) ? make_float4(0.f, 0.f, 0.f, 0.f)
                                     : sP[cur][c + 1];
    Inc[c * NV4 + n4] = inc;
}

// ---- K3: replay chunks with exact incoming advantage ----------------------
__global__ __launch_bounds__(256) void gae_out(
    const float4* __restrict__ rewards,
    const float4* __restrict__ values,
    const float4* __restrict__ dones,
    const float4* __restrict__ Inc,
    float4* __restrict__ out)          // [2*T_LEN][NV4]: advantages, returns
{
    const int idx = blockIdx.x * blockDim.x + threadIdx.x;
    const int n4 = idx & (NV4 - 1);
    const int c  = idx >> 10;
    const int t_hi = c * CHUNK_L + (CHUNK_L - 1);

    float4 adv = Inc[idx];

    float4 v_next, d_next;
    if (c == N_CHUNKS - 1) {
        v_next = make_float4(0.f, 0.f, 0.f, 0.f);
        d_next = make_float4(1.f, 1.f, 1.f, 1.f);
    } else {
        v_next = values[(t_hi + 1) * NV4 + n4];
        d_next = dones [(t_hi + 1) * NV4 + n4];
    }

    #pragma unroll
    for (int i = 0; i < CHUNK_L; ++i) {
        const int t = t_hi - i;
        const float4 r = rewards[t * NV4 + n4];
        const float4 v = values [t * NV4 + n4];
        const float4 d = dones  [t * NV4 + n4];
        float4 ret;
        #define STEP(X) { \
            const float nt    = 1.0f - d_next.X; \
            const float delta = fmaf(GAMMA * v_next.X, nt, r.X) - v.X; \
            const float co    = GL * nt; \
            adv.X = fmaf(co, adv.X, delta); \
            ret.X = adv.X + v.X; \
            v_next.X = v.X; d_next.X = d.X; }
        STEP(x) STEP(y) STEP(z) STEP(w)
        #undef STEP
        out[t * NV4 + n4]           = adv;   // advantages
        out[(T_LEN + t) * NV4 + n4] = ret;   // returns
    }
}

// ---- fallback: proven round-0 2-kernel path (ws too small) ----------------
#define FB_CHUNKS 128
#define FB_L      16

__global__ __launch_bounds__(256) void gae_phase1_fb(
    const float4* __restrict__ rewards,
    const float4* __restrict__ values,
    const float4* __restrict__ dones,
    float4* __restrict__ Aout,
    float4* __restrict__ Pout)
{
    const int idx = blockIdx.x * blockDim.x + threadIdx.x;
    const int n4 = idx & (NV4 - 1);
    const int c  = idx >> 10;
    const int t_hi = c * FB_L + (FB_L - 1);

    float4 v_next, d_next;
    if (c == FB_CHUNKS - 1) {
        v_next = make_float4(0.f, 0.f, 0.f, 0.f);
        d_next = make_float4(1.f, 1.f, 1.f, 1.f);
    } else {
        v_next = values[(t_hi + 1) * NV4 + n4];
        d_next = dones [(t_hi + 1) * NV4 + n4];
    }
    float4 A = make_float4(1.f, 1.f, 1.f, 1.f);
    float4 P = make_float4(0.f, 0.f, 0.f, 0.f);
    #pragma unroll
    for (int i = 0; i < FB_L; ++i) {
        const int t = t_hi - i;
        const float4 r = rewards[t * NV4 + n4];
        const float4 v = values [t * NV4 + n4];
        const float4 d = dones  [t * NV4 + n4];
        #define STEP(X) { \
            const float nt    = 1.0f - d_next.X; \
            const float delta = fmaf(GAMMA * v_next.X, nt, r.X) - v.X; \
            const float co    = GL * nt; \
            P.X = fmaf(co, P.X, delta); \
            A.X = co * A.X; \
            v_next.X = v.X; d_next.X = d.X; }
        STEP(x) STEP(y) STEP(z) STEP(w)
        #undef STEP
    }
    Aout[idx] = A;
    Pout[idx] = P;
}

__global__ __launch_bounds__(256) void gae_phase23_fb(
    const float4* __restrict__ rewards,
    const float4* __restrict__ values,
    const float4* __restrict__ dones,
    const float4* __restrict__ Ain,
    const float4* __restrict__ Pin,
    float4* __restrict__ out)
{
    const int idx = blockIdx.x * blockDim.x + threadIdx.x;
    const int n4 = idx & (NV4 - 1);
    const int c  = idx >> 10;
    const int t_hi = c * FB_L + (FB_L - 1);

    float4 adv = make_float4(0.f, 0.f, 0.f, 0.f);
    #pragma unroll 4
    for (int c2 = FB_CHUNKS - 1; c2 > c; --c2) {
        const float4 a = Ain[c2 * NV4 + n4];
        const float4 p = Pin[c2 * NV4 + n4];
        adv.x = fmaf(a.x, adv.x, p.x);
        adv.y = fmaf(a.y, adv.y, p.y);
        adv.z = fmaf(a.z, adv.z, p.z);
        adv.w = fmaf(a.w, adv.w, p.w);
    }
    float4 v_next, d_next;
    if (c == FB_CHUNKS - 1) {
        v_next = make_float4(0.f, 0.f, 0.f, 0.f);
        d_next = make_float4(1.f, 1.f, 1.f, 1.f);
    } else {
        v_next = values[(t_hi + 1) * NV4 + n4];
        d_next = dones [(t_hi + 1) * NV4 + n4];
    }
    #pragma unroll
    for (int i = 0; i < FB_L; ++i) {
        const int t = t_hi - i;
        const float4 r = rewards[t * NV4 + n4];
        const float4 v = values [t * NV4 + n4];
        const float4 d = dones  [t * NV4 + n4];
        float4 ret;
        #define STEP(X) { \
            const float nt    = 1.0f - d_next.X; \
            const float delta = fmaf(GAMMA * v_next.X, nt, r.X) - v.X; \
            const float co    = GL * nt; \
            adv.X = fmaf(co, adv.X, delta); \
            ret.X = adv.X + v.X; \
            v_next.X = v.X; d_next.X = d.X; }
        STEP(x) STEP(y) STEP(z) STEP(w)
        #undef STEP
        out[t * NV4 + n4]           = adv;
        out[(T_LEN + t) * NV4 + n4] = ret;
    }
}

extern "C" void kernel_launch(void* const* d_in, const int* in_sizes, int n_in,
                              void* d_out, int out_size, void* d_ws, size_t ws_size,
                              hipStream_t stream) {
    const float4* rewards = (const float4*)d_in[0];
    const float4* values  = (const float4*)d_in[1];
    const float4* dones   = (const float4*)d_in[2];
    float4* out = (float4*)d_out;

    // Workspace: A | P | Inc, each N_CHUNKS*NV4 float4 = 8 MiB (24 MiB total).
    // All fully written before read (0xAA poison safe). No memsets needed.
    const size_t entries = (size_t)N_CHUNKS * NV4;
    float4* A   = (float4*)d_ws;
    float4* P   = A + entries;
    float4* Inc = P + entries;

    if (ws_size >= 3 * entries * sizeof(float4)) {
        gae_sum <<<NBLK1, 256, 0, stream>>>(rewards, values, dones, A, P);
        gae_scan<<<NV4,   512, 0, stream>>>(A, P, Inc);
        gae_out <<<NBLK1, 256, 0, stream>>>(rewards, values, dones, Inc, out);
    } else {
        // Fallback: proven 2-kernel path (A/P only, 2 MiB each at C=128).
        gae_phase1_fb <<<(FB_CHUNKS * NV4) / 256, 256, 0, stream>>>(
            rewards, values, dones, A, P);
        gae_phase23_fb<<<(FB_CHUNKS * NV4) / 256, 256, 0, stream>>>(
            rewards, values, dones, A, P, out);
    }
}